// Round 6
// baseline (205.499 us; speedup 1.0000x reference)
//
#include <hip/hip_runtime.h>

typedef unsigned int u32;
typedef unsigned long long u64;
typedef unsigned short u16;

#define DEV __device__ __forceinline__

typedef __attribute__((ext_vector_type(8))) short bf16x8;
typedef __attribute__((ext_vector_type(16))) float f32x16;

// ---------- helpers ----------
DEV u16 f2bf(float x) {                      // fp32 -> bf16 RNE
  u32 u = __float_as_uint(x);
  u32 r = u + 0x7fffu + ((u >> 16) & 1u);
  return (u16)(r >> 16);
}
DEV float bf2f(u16 h) { return __uint_as_float((u32)h << 16); }
DEV float bflo(u32 d) { return __uint_as_float(d << 16); }
DEV float bfhi(u32 d) { return __uint_as_float(d & 0xffff0000u); }
DEV u64 sortable64(double f) {               // monotonic f64 -> u64
  long long b = __double_as_longlong(f);
  return (u64)b ^ (u64)((b >> 63) | (long long)0x8000000000000000ll);
}
// fp64 exact-selection distance (float products are exact in f64)
DEV double ddist(double qx, double qy, double qz, double qd2,
                 float mxf, float myf, float mzf) {
  double cx = (double)mxf, cy = (double)myf, cz = (double)mzf;
  double cd2 = cx * cx + cy * cy + cz * cz;
  double dot = cx * qx + cy * qy + cz * qz;
  return (qd2 + cd2) - 2.0 * dot;
}

#define NB 2
#define NN 8192
#define NC 128
#define KK 21
// MFMA screening: st = cd2 - 2*q.c via two-term bf16 splits (all 4 cross
// terms + split cd2). Worst-case two-sided error 2e <= ~8.2e-3 (|x|<=4.2);
// MARGIN 0.012 > 2e guarantees the fp64 top-21 set survives screening.
// Survivor capacity 256 (mean ~32, dense-region tail ~100) removes the
// R5 overflow failure mode.
#define MARGIN 0.012f
#define BF16_ONE ((u16)0x3F80)

// ---------- K0: fold BN into weights ----------
__global__ __launch_bounds__(256) void k_prep(
    const float* __restrict__ Wf, const float* __restrict__ gf, const float* __restrict__ bf_,
    const float* __restrict__ mf, const float* __restrict__ vf,
    const float* __restrict__ Wg, const float* __restrict__ gg, const float* __restrict__ bg,
    const float* __restrict__ mg, const float* __restrict__ vg,
    u16* __restrict__ Wt, float* __restrict__ beta_f,
    float* __restrict__ Wgu, float* __restrict__ Wgv, float* __restrict__ beta_g) {
  int g = blockIdx.x * 256 + threadIdx.x;     // 0..32767
  int c = g >> 8, o = g & 255;
  float val;
  if (o < 128) {
    float inv = gf[o] / sqrtf(vf[o] + 1e-5f);
    val = inv * (Wf[o * 256 + c] - Wf[o * 256 + c + 128]);
  } else {
    int o2 = o - 128;
    float inv = gf[o2] / sqrtf(vf[o2] + 1e-5f);
    val = inv * Wf[o2 * 256 + c + 128];
  }
  Wt[c * 256 + o] = f2bf(val);
  if (g < 128) {
    float inv = gf[g] / sqrtf(vf[g] + 1e-5f);
    beta_f[g] = bf_[g] - mf[g] * inv;
  } else if (g < 256) {
    int oo = g - 128;
    float invg = gg[oo] / sqrtf(vg[oo] + 1e-5f);
#pragma unroll
    for (int d = 0; d < 3; ++d) {
      Wgu[oo * 3 + d] = invg * (Wg[oo * 6 + d] - Wg[oo * 6 + 3 + d]);
      Wgv[oo * 3 + d] = invg * Wg[oo * 6 + 3 + d];
    }
    beta_g[oo] = bg[oo] - mg[oo] * invg;
  }
}

// ---------- K1geo ----------
__global__ __launch_bounds__(256) void k_geo(
    const float* __restrict__ xyz, const float* __restrict__ Wgu, const float* __restrict__ Wgv,
    const float* __restrict__ beta_g, u32* __restrict__ ucat, u32* __restrict__ vcat) {
  int g = blockIdx.x * 256 + threadIdx.x;     // < 16384*64
  int p = g >> 6, oc = g & 63;
  const float* xp = xyz + p * 3;
  float X = xp[0], Y = xp[1], Z = xp[2];
  u32 du = 0, dv = 0;
#pragma unroll
  for (int h = 0; h < 2; ++h) {
    int o = oc * 2 + h;
    float ug = X * Wgu[o * 3] + Y * Wgu[o * 3 + 1] + Z * Wgu[o * 3 + 2] + beta_g[o];
    float vv = X * Wgv[o * 3] + Y * Wgv[o * 3 + 1] + Z * Wgv[o * 3 + 2];
    du |= (u32)f2bf(ug) << (16 * h);
    dv |= (u32)f2bf(vv) << (16 * h);
  }
  ucat[p * 128 + oc] = du;
  vcat[p * 128 + oc] = dv;
}

// ---------- K1f: feat branch GEMM ----------
__global__ __launch_bounds__(256) void k_feat(
    const float* __restrict__ f, const u32* __restrict__ Wt32, const float* __restrict__ beta_f,
    u32* __restrict__ ucat, u32* __restrict__ vcat) {
  __shared__ u32 sW[128 * 128];
  __shared__ float sF[128][68];

  const int t = threadIdx.x;
  const int b = blockIdx.x >> 7;
  const int n0 = (blockIdx.x & 127) << 6;
  const int boff = b * (NC * NN);

#pragma unroll
  for (int k = 0; k < 64; ++k) sW[t + (k << 8)] = Wt32[t + (k << 8)];
#pragma unroll
  for (int k = 0; k < 32; ++k) {
    int i = t + (k << 8);
    int c = i >> 6, col = i & 63;
    sF[c][col] = f[boff + c * NN + n0 + col];
  }
  __syncthreads();

  const int w = t >> 6, lane = t & 63;
  const int og = lane >> 3, pg = lane & 7;
  const int o0 = w * 64 + og * 8;
  const int p0 = pg * 8;

  float acc[8][8];
#pragma unroll
  for (int a = 0; a < 8; ++a)
#pragma unroll
    for (int p = 0; p < 8; ++p) acc[a][p] = 0.0f;

  for (int c = 0; c < 128; ++c) {
    float4 fa = *(const float4*)&sF[c][p0];
    float4 fb = *(const float4*)&sF[c][p0 + 4];
    uint4 wr = *(const uint4*)&sW[c * 128 + (o0 >> 1)];
    float wv[8] = {bflo(wr.x), bfhi(wr.x), bflo(wr.y), bfhi(wr.y),
                   bflo(wr.z), bfhi(wr.z), bflo(wr.w), bfhi(wr.w)};
    float fv[8] = {fa.x, fa.y, fa.z, fa.w, fb.x, fb.y, fb.z, fb.w};
#pragma unroll
    for (int a = 0; a < 8; ++a)
#pragma unroll
      for (int p = 0; p < 8; ++p) acc[a][p] = __builtin_fmaf(wv[a], fv[p], acc[a][p]);
  }

  const int ochan = o0 & 127;
  const bool is_u = (o0 < 128);
  float bet[8];
#pragma unroll
  for (int a = 0; a < 8; ++a) bet[a] = is_u ? beta_f[ochan + a] : 0.0f;
  u32* dstbase = is_u ? ucat : vcat;
#pragma unroll
  for (int p = 0; p < 8; ++p) {
    int pt = (b << 13) + n0 + p0 + p;
    u32 d0 = (u32)f2bf(acc[0][p] + bet[0]) | ((u32)f2bf(acc[1][p] + bet[1]) << 16);
    u32 d1 = (u32)f2bf(acc[2][p] + bet[2]) | ((u32)f2bf(acc[3][p] + bet[3]) << 16);
    u32 d2 = (u32)f2bf(acc[4][p] + bet[4]) | ((u32)f2bf(acc[5][p] + bet[5]) << 16);
    u32 d3 = (u32)f2bf(acc[6][p] + bet[6]) | ((u32)f2bf(acc[7][p] + bet[7]) << 16);
    *(uint4*)&dstbase[pt * 128 + 64 + (ochan >> 1)] = make_uint4(d0, d1, d2, d3);
  }
}

// ---------- K_pack: per-point B-fragment pre-pack for the KNN MFMA ----------
// Per-point K-vector (16 bf16): k0..2=ch k3..5=ch k6..8=cl k9=cd2h k10=cd2l
// k11..13=cl k14,15=0, stored per 32-cand group in B-fragment order
// [half][n][8] so lane l loads 16B at g*1024 + l*16 (coalesced).
__global__ __launch_bounds__(256) void k_pack(const float* __restrict__ xyz,
                                              u16* __restrict__ pack) {
  int p = blockIdx.x * 256 + threadIdx.x;     // 0..16383
  const float* xp = xyz + p * 3;
  float x = xp[0], y = xp[1], z = xp[2];
  u16 hx = f2bf(x), hy = f2bf(y), hz = f2bf(z);
  u16 lx = f2bf(x - bf2f(hx)), ly = f2bf(y - bf2f(hy)), lz = f2bf(z - bf2f(hz));
  float cd2 = __builtin_fmaf(x, x, __builtin_fmaf(y, y, z * z));
  u16 dh = f2bf(cd2), dl = f2bf(cd2 - bf2f(dh));

  int g = p >> 5, n = p & 31;
  u32* h0 = (u32*)(pack + (size_t)g * 512 + n * 8);
  u32* h1 = (u32*)(pack + (size_t)g * 512 + 256 + n * 8);
  h0[0] = (u32)hx | ((u32)hy << 16);
  h0[1] = (u32)hz | ((u32)hx << 16);
  h0[2] = (u32)hy | ((u32)hz << 16);
  h0[3] = (u32)lx | ((u32)ly << 16);
  h1[0] = (u32)lz | ((u32)dh << 16);
  h1[1] = (u32)dl | ((u32)lx << 16);
  h1[2] = (u32)ly | ((u32)lz << 16);
  h1[3] = 0u;
}

DEV u64 surv_key(const u16* __restrict__ srow, u32 cnt, int pos,
                 const float* __restrict__ X,
                 double Qx, double Qy, double Qz, double Qd2) {
  bool vv = (u32)pos < cnt;
  u32 m = vv ? (u32)srow[pos] : 0u;
  double ss = ddist(Qx, Qy, Qz, Qd2, X[m * 3], X[m * 3 + 1], X[m * 3 + 2]);
  return vv ? ((sortable64(ss) & 0xFFFFFFFFFFFFE000ull) | (u64)m) : ~0ull;
}

// ---------- K2: exact KNN (k=21) — MFMA screening + fp64 exact selection ----
// mfma_f32_32x32x16_bf16: A[m=lane&31][k=(lane>>5)*8+j],
// B[n=lane&31][k=(lane>>5)*8+j], C/D col=lane&31,
// row=(reg&3)+8*(reg>>2)+4*(lane>>5)  (layouts confirmed working in R5:
// failure mode there was survivor overflow, not layout).
__global__ __launch_bounds__(256, 2) void k_knn(const float* __restrict__ xyz,
                                                const u16* __restrict__ pack,
                                                int* __restrict__ knn) {
  __shared__ float smin[32][128];             // 16 KB per-(query,subset) minima
  __shared__ u16 ssurv[32][256];              // 16 KB survivors
  __shared__ float sthr[32];
  __shared__ u32 scnt[32];

  const int t = threadIdx.x, w = t >> 6, lane = t & 63;
  const int blk = blockIdx.x;                 // 0..511
  const int b = blk >> 8;                     // 256 blocks/batch
  const int n0 = (blk & 255) << 5;            // 32 queries/block
  const float* X = xyz + b * (NN * 3);
  const u16* PB = pack + (size_t)b * NN * 16;

  if (t < 32) scnt[t] = 0u;

  // ---- build A fragment (this wave's 32 queries) ----
  const int mq = lane & 31, h = lane >> 5;
  union { u16 u[8]; bf16x8 v; } afr;
  {
    int q = n0 + mq;
    float qx = -2.0f * X[q * 3], qy = -2.0f * X[q * 3 + 1], qz = -2.0f * X[q * 3 + 2];
    u16 hx = f2bf(qx), hy = f2bf(qy), hz = f2bf(qz);
    u16 lx = f2bf(qx - bf2f(hx)), ly = f2bf(qy - bf2f(hy)), lz = f2bf(qz - bf2f(hz));
    if (h == 0) {
      afr.u[0] = hx; afr.u[1] = hy; afr.u[2] = hz; afr.u[3] = lx;
      afr.u[4] = ly; afr.u[5] = lz; afr.u[6] = hx; afr.u[7] = hy;
    } else {
      afr.u[0] = hz; afr.u[1] = BF16_ONE; afr.u[2] = BF16_ONE; afr.u[3] = lx;
      afr.u[4] = ly; afr.u[5] = lz; afr.u[6] = 0; afr.u[7] = 0;
    }
  }

  f32x16 zacc = {0.f, 0.f, 0.f, 0.f, 0.f, 0.f, 0.f, 0.f,
                 0.f, 0.f, 0.f, 0.f, 0.f, 0.f, 0.f, 0.f};

  // ---- pass A: per-(lane,reg) running min over this wave's tile quarter ----
  float mn[16];
#pragma unroll
  for (int r = 0; r < 16; ++r) mn[r] = __builtin_inff();

  for (int i0 = 0; i0 < 64; i0 += 8) {
    uint4 braw[8];
#pragma unroll
    for (int j = 0; j < 8; ++j) {
      int tile = w + 4 * (i0 + j);
      braw[j] = *(const uint4*)(PB + (size_t)tile * 512 + lane * 8);
    }
#pragma unroll
    for (int j = 0; j < 8; ++j) {
      union { uint4 r; bf16x8 v; } bf; bf.r = braw[j];
      f32x16 d = __builtin_amdgcn_mfma_f32_32x32x16_bf16(afr.v, bf.v, zacc, 0, 0, 0);
#pragma unroll
      for (int r = 0; r < 16; ++r) mn[r] = fminf(mn[r], d[r]);
    }
  }

  // subset minima: query row = (reg&3)+8*(reg>>2)+4*h, subset col = w*32+mq
  // 128 disjoint subsets of 64 candidates each, full coverage.
#pragma unroll
  for (int r = 0; r < 16; ++r) {
    int row = (r & 3) + 8 * (r >> 2) + 4 * h;
    smin[row][w * 32 + mq] = mn[r];
  }
  __syncthreads();

  // ---- threshold/row: 21st smallest of 64 pair-min (disjoint subsets) ----
  for (int i = 0; i < 8; ++i) {
    int row = w * 8 + i;
    float v = fminf(smin[row][lane], smin[row][lane + 64]);
#pragma unroll
    for (int k = 2; k <= 64; k <<= 1) {
#pragma unroll
      for (int j = k >> 1; j > 0; j >>= 1) {
        float p = __shfl_xor(v, j);
        bool takeMin = (((lane & k) == 0) == ((lane & j) == 0));
        v = takeMin ? fminf(v, p) : fmaxf(v, p);
      }
    }
    float t20 = __shfl(v, 20);                // shfl OUTSIDE divergent branch
    if (lane == 0) sthr[row] = t20 + MARGIN;
  }
  __syncthreads();

  float thr[16];
#pragma unroll
  for (int r = 0; r < 16; ++r) thr[r] = sthr[(r & 3) + 8 * (r >> 2) + 4 * h];

  // ---- pass B: rescan quarter, push survivors ----
  for (int i0 = 0; i0 < 64; i0 += 4) {
    uint4 braw[4];
#pragma unroll
    for (int j = 0; j < 4; ++j) {
      int tile = w + 4 * (i0 + j);
      braw[j] = *(const uint4*)(PB + (size_t)tile * 512 + lane * 8);
    }
#pragma unroll
    for (int j = 0; j < 4; ++j) {
      int tile = w + 4 * (i0 + j);
      union { uint4 r; bf16x8 v; } bf; bf.r = braw[j];
      f32x16 d = __builtin_amdgcn_mfma_f32_32x32x16_bf16(afr.v, bf.v, zacc, 0, 0, 0);
#pragma unroll
      for (int r = 0; r < 16; ++r) {
        if (d[r] <= thr[r]) {
          int row = (r & 3) + 8 * (r >> 2) + 4 * h;
          u32 slot = atomicAdd(&scnt[row], 1u);
          if (slot < 256u) ssurv[row][slot] = (u16)(tile * 32 + mq);
        }
      }
    }
  }
  __syncthreads();

  // ---- selection: exact top-21 by fp64 (dist, idx); wave w owns 8 rows ----
#pragma unroll 1
  for (int i = 0; i < 8; ++i) {
    const int qq = (w << 3) + i;
    const int q = n0 + qq;
    double Qx = (double)X[q * 3], Qy = (double)X[q * 3 + 1], Qz = (double)X[q * 3 + 2];
    double Qd2 = Qx * Qx + Qy * Qy + Qz * Qz;
    u32 cnt = scnt[qq]; if (cnt > 256u) cnt = 256u;
    const u16* srow = ssurv[qq];
    int* outp = knn + ((b << 13) + q) * KK;

    u64 k0 = surv_key(srow, cnt, lane, X, Qx, Qy, Qz, Qd2);

    if (cnt <= 64u) {
      u64 v = k0;
#pragma unroll
      for (int k = 2; k <= 64; k <<= 1) {
#pragma unroll
        for (int j = k >> 1; j > 0; j >>= 1) {
          u64 p = __shfl_xor(v, j);
          bool takeMin = (((lane & k) == 0) == ((lane & j) == 0));
          bool pl = p < v;
          u64 mnv = pl ? p : v;
          u64 mxv = pl ? v : p;
          v = takeMin ? mnv : mxv;
        }
      }
      if (lane < KK) outp[lane] = (int)(v & 8191ull);
    } else if (cnt <= 128u) {
      u64 k1 = surv_key(srow, cnt, lane + 64, X, Qx, Qy, Qz, Qd2);
      u32 selm = 0;
      for (int r = 0; r < KK; ++r) {
        u64 mk = (k0 < k1) ? k0 : k1;
#pragma unroll
        for (int j = 32; j > 0; j >>= 1) {
          u64 p = __shfl_xor(mk, j);
          if (p < mk) mk = p;
        }
        if (k0 == mk) k0 = ~0ull;
        else if (k1 == mk) k1 = ~0ull;
        if (lane == r) selm = (u32)(mk & 8191ull);
      }
      if (lane < KK) outp[lane] = (int)selm;
    } else {
      u64 k1 = surv_key(srow, cnt, lane + 64, X, Qx, Qy, Qz, Qd2);
      u64 k2 = surv_key(srow, cnt, lane + 128, X, Qx, Qy, Qz, Qd2);
      u64 k3 = surv_key(srow, cnt, lane + 192, X, Qx, Qy, Qz, Qd2);
      u32 selm = 0;
      for (int r = 0; r < KK; ++r) {
        u64 m01 = (k0 < k1) ? k0 : k1;
        u64 m23 = (k2 < k3) ? k2 : k3;
        u64 mk = (m01 < m23) ? m01 : m23;
#pragma unroll
        for (int j = 32; j > 0; j >>= 1) {
          u64 p = __shfl_xor(mk, j);
          if (p < mk) mk = p;
        }
        if (k0 == mk) k0 = ~0ull;
        else if (k1 == mk) k1 = ~0ull;
        else if (k2 == mk) k2 = ~0ull;
        else if (k3 == mk) k3 = ~0ull;
        if (lane == r) selm = (u32)(mk & 8191ull);
      }
      if (lane < KK) outp[lane] = (int)selm;
    }
  }
}

// ---------- K3: gather + max + relu + transpose-write ----------
__global__ __launch_bounds__(256) void k_gather(
    const u32* __restrict__ ucat, const u32* __restrict__ vcat,
    const int* __restrict__ knn, float* __restrict__ out) {
  __shared__ float tr[64 * 258];

  const int t = threadIdx.x;
  const int b = blockIdx.x >> 7;
  const int n0 = (blockIdx.x & 127) << 6;
  const int w = t >> 6, lane = t & 63;
  const int which = w >> 1;
  const int lo = ((w & 1) << 6) | lane;

  for (int step = 0; step < 32; ++step) {
    int qq = step * 2 + which;
    int q = n0 + qq;
    const int* ip = knn + ((b << 13) + q) * KK;
    float a0 = -__builtin_inff(), a1 = -__builtin_inff();
#pragma unroll
    for (int k = 0; k < KK; ++k) {
      int p = ip[k];
      u32 d = vcat[(((b << 13) + p) << 7) + lo];
      a0 = fmaxf(a0, bflo(d));
      a1 = fmaxf(a1, bfhi(d));
    }
    u32 u = ucat[(((b << 13) + q) << 7) + lo];
    float r0 = fmaxf(bflo(u) + a0, 0.0f);
    float r1 = fmaxf(bfhi(u) + a1, 0.0f);
    *(float2*)&tr[qq * 258 + 2 * lo] = make_float2(r0, r1);
  }
  __syncthreads();

  float* ob = out + b * (256 * NN);
  for (int i = 0; i < 64; ++i) {
    int o = (w << 6) + i;
    ob[o * NN + n0 + lane] = tr[lane * 258 + o];
  }
}

// ---------- launch ----------
extern "C" void kernel_launch(void* const* d_in, const int* in_sizes, int n_in,
                              void* d_out, int out_size, void* d_ws, size_t ws_size,
                              hipStream_t stream) {
  const float* xyz = (const float*)d_in[0];
  const float* f   = (const float*)d_in[1];
  const float* Wg  = (const float*)d_in[2];
  const float* gg  = (const float*)d_in[3];
  const float* bg  = (const float*)d_in[4];
  const float* mg  = (const float*)d_in[5];
  const float* vg  = (const float*)d_in[6];
  const float* Wf  = (const float*)d_in[7];
  const float* gf  = (const float*)d_in[8];
  const float* bf_ = (const float*)d_in[9];
  const float* mf  = (const float*)d_in[10];
  const float* vf  = (const float*)d_in[11];

  char* ws = (char*)d_ws;
  u16*   Wt     = (u16*)ws;                               // 65536 B
  float* beta_f = (float*)(ws + 65536);
  float* Wgu    = (float*)(ws + 66048);
  float* Wgv    = (float*)(ws + 67584);
  float* beta_g = (float*)(ws + 69120);
  u32*   ucat   = (u32*)(ws + 69632);                     // 8 MB
  u32*   vcat   = (u32*)(ws + 69632 + 8388608);           // 8 MB
  int*   knn    = (int*)(ws + 16846848);                  // 1.376 MB
  u16*   pack   = (u16*)(ws + 18223104);                  // 512 KB
  float* out    = (float*)d_out;

  if (ws_size < (size_t)(18223104 + 524288)) return;

  k_prep<<<dim3(128), dim3(256), 0, stream>>>(Wf, gf, bf_, mf, vf, Wg, gg, bg, mg, vg,
                                              Wt, beta_f, Wgu, Wgv, beta_g);
  k_geo<<<dim3(4096), dim3(256), 0, stream>>>(xyz, Wgu, Wgv, beta_g, ucat, vcat);
  k_feat<<<dim3(256), dim3(256), 0, stream>>>(f, (const u32*)Wt, beta_f, ucat, vcat);
  k_pack<<<dim3(64), dim3(256), 0, stream>>>(xyz, pack);
  k_knn<<<dim3(512), dim3(256), 0, stream>>>(xyz, (const u16*)pack, knn);
  k_gather<<<dim3(256), dim3(256), 0, stream>>>(ucat, vcat, knn, out);
}